// Round 1
// baseline (398.264 us; speedup 1.0000x reference)
//
#include <hip/hip_runtime.h>
#include <hip/hip_bf16.h>

// BPNN: B=512, N=2048, F=64, T=4, H1=64, H2=32.
// out[b] = sum_n MLP_{t[n]}(x[b,n,:]), MLP = silu(W0 x+b0) -> silu(W1 h+b1) -> w2.h+b2
//
// Design: type depends only on n, so an MFMA M-tile = 16 b-values at fixed n
// shares one weight matrix. Wave handles 16 b x 32 n; block = 4 waves (128 n).
// Grid (16,32) = 512 blocks = 2/CU (LDS-limited: exactly 64 KB/block).
// All-type weights staged to LDS as bf16; rows padded (72 / 68) for
// conflict-free ds_read_b128 / b64.

#define B_ 512
#define N_ 2048
#define F_ 64
#define T_ 4
#define H1_ 64
#define H2_ 32

#define BT 16          // b-tile (MFMA M)
#define WAVES 4
#define NPW 32         // n per wave
#define NCHUNK (WAVES * NPW)   // 128 n per block

typedef __attribute__((ext_vector_type(8))) short bf16x8;
typedef __attribute__((ext_vector_type(4))) short bf16x4;
typedef __attribute__((ext_vector_type(4))) float f32x4;

__device__ inline float silu_f(float v) {
    return v * __builtin_amdgcn_rcpf(1.0f + __expf(-v));
}

__device__ inline bf16x8 pack8(float4 a, float4 b) {
    union { __hip_bfloat162 h[4]; bf16x8 v; } u;
    u.h[0] = __float22bfloat162_rn({a.x, a.y});
    u.h[1] = __float22bfloat162_rn({a.z, a.w});
    u.h[2] = __float22bfloat162_rn({b.x, b.y});
    u.h[3] = __float22bfloat162_rn({b.z, b.w});
    return u.v;
}

__global__ __launch_bounds__(256, 4) void bpnn_kernel(
    const float* __restrict__ x, const int* __restrict__ an,
    const float* __restrict__ w0, const float* __restrict__ b0,
    const float* __restrict__ w1, const float* __restrict__ b1,
    const float* __restrict__ w2, const float* __restrict__ b2,
    float* __restrict__ out)
{
    // LDS budget = exactly 65536 B (2 blocks/CU on 160 KiB LDS).
    __shared__ __align__(16) __hip_bfloat16 w0s[T_][H1_][72];   // 36864  pad72: 16B-aligned rows, 2-way max conflict
    __shared__ __align__(16) __hip_bfloat16 w1s[T_][H2_][72];   // 18432
    __shared__ __align__(16) __hip_bfloat16 h1s[WAVES][BT][68]; // 8704   pad68: conflict-free b16 writes / b64 reads
    __shared__ __align__(16) __hip_bfloat16 w2s[T_][H2_];       // 256
    __shared__ __align__(16) __hip_bfloat16 b0s[T_][H1_];       // 512
    __shared__ __align__(16) __hip_bfloat16 b1s[T_][H2_];       // 256
    __shared__ __align__(16) int ans[NCHUNK];                   // 512 (re-used as float red[16] at the end)

    const int tid = threadIdx.x;

    // ---- stage weights (fp32 global -> bf16 LDS), one-time per block ----
    for (int i = tid; i < T_ * H1_ * F_; i += 256)
        w0s[i >> 12][(i >> 6) & 63][i & 63] = __float2bfloat16(w0[i]);
    for (int i = tid; i < T_ * H2_ * H1_; i += 256)
        w1s[i >> 11][(i >> 6) & 31][i & 63] = __float2bfloat16(w1[i]);
    if (tid < T_ * H2_) w2s[tid >> 5][tid & 31] = __float2bfloat16(w2[tid]);
    if (tid < T_ * H1_) b0s[tid >> 6][tid & 63] = __float2bfloat16(b0[tid]);
    if (tid < T_ * H2_) b1s[tid >> 5][tid & 31] = __float2bfloat16(b1[tid]);
    if (tid < NCHUNK)   ans[tid] = an[blockIdx.x * NCHUNK + tid];
    const float b2r0 = b2[0], b2r1 = b2[1], b2r2 = b2[2], b2r3 = b2[3];
    __syncthreads();

    const int wave = tid >> 6;
    const int lane = tid & 63;
    const int lr   = lane & 15;   // M-row (A) / N-col (B,C)
    const int q    = lane >> 4;   // quad
    const int b0i  = blockIdx.y * BT;
    const float* xrow = x + ((size_t)(b0i + lr) * N_) * F_ + q * 8;

    float esum[4] = {0.f, 0.f, 0.f, 0.f};
    float bsum = 0.f;

    for (int it = 0; it < NPW; ++it) {
        const int nloc = wave * NPW + it;
        int t = ans[nloc];
        t = __builtin_amdgcn_readfirstlane(t);

        // A-frags for layer 0: lane holds x[b = b0i+lr][k = q*8+j (+32)]
        const float4* xp = reinterpret_cast<const float4*>(xrow + (size_t)(blockIdx.x * NCHUNK + nloc) * F_);
        float4 xa = xp[0], xb = xp[1], xc = xp[8], xd = xp[9];
        bf16x8 a0 = pack8(xa, xb);
        bf16x8 a1 = pack8(xc, xd);

        // ---- layer 0: [16b x 64] = A[16x64] * W0^T[64x64] ----
        f32x4 acc[4] = {{0,0,0,0},{0,0,0,0},{0,0,0,0},{0,0,0,0}};
#pragma unroll
        for (int nt = 0; nt < 4; ++nt) {
            bf16x8 bw0 = *reinterpret_cast<const bf16x8*>(&w0s[t][nt * 16 + lr][q * 8]);
            acc[nt] = __builtin_amdgcn_mfma_f32_16x16x32_bf16(a0, bw0, acc[nt], 0, 0, 0);
            bf16x8 bw1 = *reinterpret_cast<const bf16x8*>(&w0s[t][nt * 16 + lr][32 + q * 8]);
            acc[nt] = __builtin_amdgcn_mfma_f32_16x16x32_bf16(a1, bw1, acc[nt], 0, 0, 0);
        }
        // bias + silu, C-layout (row b = q*4+r, col h = nt*16+lr) -> LDS for A-layout reload
#pragma unroll
        for (int nt = 0; nt < 4; ++nt) {
            float bias = __bfloat162float(b0s[t][nt * 16 + lr]);
#pragma unroll
            for (int r = 0; r < 4; ++r) {
                float v = silu_f(acc[nt][r] + bias);
                h1s[wave][q * 4 + r][nt * 16 + lr] = __float2bfloat16(v);
            }
        }
        __builtin_amdgcn_wave_barrier();  // order LDS write->read (DS ops in-order per wave)

        bf16x4 lo0 = *reinterpret_cast<const bf16x4*>(&h1s[wave][lr][q * 8]);
        bf16x4 hi0 = *reinterpret_cast<const bf16x4*>(&h1s[wave][lr][q * 8 + 4]);
        bf16x4 lo1 = *reinterpret_cast<const bf16x4*>(&h1s[wave][lr][32 + q * 8]);
        bf16x4 hi1 = *reinterpret_cast<const bf16x4*>(&h1s[wave][lr][32 + q * 8 + 4]);
        bf16x8 h1a0 = __builtin_shufflevector(lo0, hi0, 0, 1, 2, 3, 4, 5, 6, 7);
        bf16x8 h1a1 = __builtin_shufflevector(lo1, hi1, 0, 1, 2, 3, 4, 5, 6, 7);
        __builtin_amdgcn_wave_barrier();

        // ---- layer 1: [16b x 32] = h1[16x64] * W1^T[64x32] ----
        f32x4 accB[2] = {{0,0,0,0},{0,0,0,0}};
#pragma unroll
        for (int nt = 0; nt < 2; ++nt) {
            bf16x8 bw0 = *reinterpret_cast<const bf16x8*>(&w1s[t][nt * 16 + lr][q * 8]);
            accB[nt] = __builtin_amdgcn_mfma_f32_16x16x32_bf16(h1a0, bw0, accB[nt], 0, 0, 0);
            bf16x8 bw1 = *reinterpret_cast<const bf16x8*>(&w1s[t][nt * 16 + lr][32 + q * 8]);
            accB[nt] = __builtin_amdgcn_mfma_f32_16x16x32_bf16(h1a1, bw1, accB[nt], 0, 0, 0);
        }
        // ---- layer 2: per-lane partial dot with w2; reduction deferred to after loop ----
        float w2v0 = __bfloat162float(w2s[t][lr]);
        float w2v1 = __bfloat162float(w2s[t][16 + lr]);
        float bi0  = __bfloat162float(b1s[t][lr]);
        float bi1  = __bfloat162float(b1s[t][16 + lr]);
#pragma unroll
        for (int r = 0; r < 4; ++r) {
            float vA = silu_f(accB[0][r] + bi0);
            float vB = silu_f(accB[1][r] + bi1);
            esum[r] += vA * w2v0 + vB * w2v1;
        }
        bsum += (t == 0) ? b2r0 : (t == 1) ? b2r1 : (t == 2) ? b2r2 : b2r3;
    }

    // butterfly-reduce esum over the 16 lanes of each quad group
#pragma unroll
    for (int m = 1; m < 16; m <<= 1) {
#pragma unroll
        for (int r = 0; r < 4; ++r) esum[r] += __shfl_xor(esum[r], m, 16);
    }

    __syncthreads();   // everyone done with ans; reuse as float red[16]
    float* red = reinterpret_cast<float*>(ans);
    if (tid < BT) red[tid] = 0.0f;
    __syncthreads();
    if (lr == 0) {
#pragma unroll
        for (int r = 0; r < 4; ++r)
            atomicAdd(&red[q * 4 + r], esum[r] + bsum);
    }
    __syncthreads();
    if (tid < BT) atomicAdd(&out[b0i + tid], red[tid]);
}

extern "C" void kernel_launch(void* const* d_in, const int* in_sizes, int n_in,
                              void* d_out, int out_size, void* d_ws, size_t ws_size,
                              hipStream_t stream) {
    const float* x  = (const float*)d_in[0];
    const int*   an = (const int*)d_in[1];
    const float* w0 = (const float*)d_in[2];
    const float* b0 = (const float*)d_in[3];
    const float* w1 = (const float*)d_in[4];
    const float* b1 = (const float*)d_in[5];
    const float* w2 = (const float*)d_in[6];
    const float* b2 = (const float*)d_in[7];
    float* out = (float*)d_out;

    hipMemsetAsync(out, 0, B_ * sizeof(float), stream);  // out accumulated via atomics
    dim3 grid(N_ / NCHUNK, B_ / BT);                     // (16, 32) = 512 blocks
    bpnn_kernel<<<grid, 256, 0, stream>>>(x, an, w0, b0, w1, b1, w2, b2, out);
}

// Round 2
// 395.531 us; speedup vs baseline: 1.0069x; 1.0069x over previous
//
#include <hip/hip_runtime.h>
#include <hip/hip_bf16.h>

// BPNN: B=512, N=2048, F=64, T=4, H1=64, H2=32.
// out[b] = sum_n MLP_{t[n]}(x[b,n,:]), MLP = silu(W0 x+b0) -> silu(W1 h+b1) -> w2.h+b2
//
// Transposed-MFMA design: compute D = W * x^T (features on M, batch b on N).
// A-frag and B-frag share the same lane mapping (m/n=lane&15, k=quad*8+j), so
// the x fragment (lane = one b-row's 8 floats) feeds the B operand directly.
// Layer-0 output C-layout: lane holds h = quad*4+reg (+16*nt), b = lane&15 ->
// 4 consecutive h at fixed b -> pack4 + ds_write_b64 into trb[b][h]; layer-1
// B-frag re-load is then a single contiguous ds_read_b128 per K-half.
// Wave = 16 b x 32 n; block = 4 waves (128 n). Grid (16,32) = 512 blocks =
// 2/CU (LDS-limited: exactly 64 KB). Row pads of 72 elems (144 B) keep all
// b64/b128 DS ops at the bank-cycle floor AND 16 B-aligned.

#define B_ 512
#define N_ 2048
#define F_ 64
#define T_ 4
#define H1_ 64
#define H2_ 32

#define BT 16          // b-tile (MFMA N dim now)
#define WAVES 4
#define NPW 32         // n per wave
#define NCHUNK (WAVES * NPW)   // 128 n per block

typedef __attribute__((ext_vector_type(8))) short bf16x8;
typedef __attribute__((ext_vector_type(4))) short bf16x4;
typedef __attribute__((ext_vector_type(4))) float f32x4;

__device__ inline float silu_f(float v) {
    return v * __builtin_amdgcn_rcpf(1.0f + __expf(-v));
}

__device__ inline bf16x8 pack8(float4 a, float4 b) {
    union { __hip_bfloat162 h[4]; bf16x8 v; } u;
    u.h[0] = __float22bfloat162_rn({a.x, a.y});
    u.h[1] = __float22bfloat162_rn({a.z, a.w});
    u.h[2] = __float22bfloat162_rn({b.x, b.y});
    u.h[3] = __float22bfloat162_rn({b.z, b.w});
    return u.v;
}

__device__ inline bf16x4 pack4(float a, float b, float c, float d) {
    union { __hip_bfloat162 h[2]; bf16x4 v; } u;
    u.h[0] = __float22bfloat162_rn({a, b});
    u.h[1] = __float22bfloat162_rn({c, d});
    return u.v;
}

__global__ __launch_bounds__(256, 2) void bpnn_kernel(
    const float* __restrict__ x, const int* __restrict__ an,
    const float* __restrict__ w0, const float* __restrict__ b0,
    const float* __restrict__ w1, const float* __restrict__ b1,
    const float* __restrict__ w2, const float* __restrict__ b2,
    float* __restrict__ out)
{
    // LDS budget = exactly 65536 B (2 blocks/CU). red[] aliases w0s post-loop.
    __shared__ __align__(16) __hip_bfloat16 w0s[T_][H1_][72];   // 36864
    __shared__ __align__(16) __hip_bfloat16 w1s[T_][H2_][72];   // 18432
    __shared__ __align__(16) __hip_bfloat16 trb[WAVES][BT][72]; // 9216 transpose buf [b][h]
    __shared__ __align__(16) __hip_bfloat16 w2s[T_][H2_];       // 256
    __shared__ __align__(16) __hip_bfloat16 b0s[T_][H1_];       // 512
    __shared__ __align__(16) __hip_bfloat16 b1s[T_][H2_];       // 256

    const int tid = threadIdx.x;

    // ---- stage weights (fp32 global -> bf16 LDS), one-time per block ----
    for (int i = tid; i < T_ * H1_ * F_; i += 256)
        w0s[i >> 12][(i >> 6) & 63][i & 63] = __float2bfloat16(w0[i]);
    for (int i = tid; i < T_ * H2_ * H1_; i += 256)
        w1s[i >> 11][(i >> 6) & 31][i & 63] = __float2bfloat16(w1[i]);
    if (tid < T_ * H2_) w2s[tid >> 5][tid & 31] = __float2bfloat16(w2[tid]);
    if (tid < T_ * H1_) b0s[tid >> 6][tid & 63] = __float2bfloat16(b0[tid]);
    if (tid < T_ * H2_) b1s[tid >> 5][tid & 31] = __float2bfloat16(b1[tid]);
    const float b2r0 = b2[0], b2r1 = b2[1], b2r2 = b2[2], b2r3 = b2[3];
    __syncthreads();

    const int wave = tid >> 6;
    const int lane = tid & 63;
    const int lr   = lane & 15;   // b-col (B,C) / h-row (A)
    const int q    = lane >> 4;   // quad
    const int b0i  = blockIdx.y * BT;
    const int gn0  = blockIdx.x * NCHUNK + wave * NPW;   // this wave's first n

    // lane's x access: row b0i+lr, fp8-col q*8; iterate n
    const float4* xp = reinterpret_cast<const float4*>(
        x + (size_t)(b0i + lr) * N_ * F_ + (size_t)gn0 * F_ + q * 8);

    __hip_bfloat16* trbw = &trb[wave][lr][0];   // this lane's transpose row (b = lr)

    float esum = 0.f;   // per-lane partial energy for b = b0i+lr
    float bsum = 0.f;

    // prefetch iter 0
    float4 pa = xp[0], pb = xp[1], pc = xp[8], pd = xp[9];
    int tpre = an[gn0];

    for (int it = 0; it < NPW; ++it) {
        const int t = __builtin_amdgcn_readfirstlane(tpre);
        float4 xa = pa, xb = pb, xc = pc, xd = pd;

        // prefetch iter it+1 (clamped; redundant on last iter)
        {
            const int nx = (it + 1 < NPW) ? (it + 1) : (NPW - 1);
            const int o = nx * 16;
            pa = xp[o]; pb = xp[o + 1]; pc = xp[o + 8]; pd = xp[o + 9];
            tpre = an[gn0 + nx];
        }

        // B-frags (x^T): lane holds x[b=b0i+lr][k = q*8+j (+32)]
        bf16x8 xb0 = pack8(xa, xb);
        bf16x8 xb1 = pack8(xc, xd);

        const __hip_bfloat16* w0t = &w0s[t][0][0];
        const __hip_bfloat16* w1t = &w1s[t][0][0];
        const int rowoff = lr * 72 + q * 8;   // A-frag base within a 16-row tile

        // ---- layer 0: D0[64h x 16b] = W0_t * x^T, 4 M-tiles x 2 K-halves ----
        f32x4 acc[4] = {{0,0,0,0},{0,0,0,0},{0,0,0,0},{0,0,0,0}};
#pragma unroll
        for (int nt = 0; nt < 4; ++nt) {
            bf16x8 aw0 = *reinterpret_cast<const bf16x8*>(w0t + nt * 16 * 72 + rowoff);
            acc[nt] = __builtin_amdgcn_mfma_f32_16x16x32_bf16(aw0, xb0, acc[nt], 0, 0, 0);
            bf16x8 aw1 = *reinterpret_cast<const bf16x8*>(w0t + nt * 16 * 72 + rowoff + 32);
            acc[nt] = __builtin_amdgcn_mfma_f32_16x16x32_bf16(aw1, xb1, acc[nt], 0, 0, 0);
        }
        // bias + silu; C-layout: lane holds h = nt*16 + q*4 + reg, b = lr.
        // 4 consecutive h at fixed b -> pack4 -> one ds_write_b64 per tile.
#pragma unroll
        for (int nt = 0; nt < 4; ++nt) {
            bf16x4 bb = *reinterpret_cast<const bf16x4*>(&b0s[t][nt * 16 + q * 4]);
            float v0 = silu_f(acc[nt][0] + __bfloat162float(((__hip_bfloat16*)&bb)[0]));
            float v1 = silu_f(acc[nt][1] + __bfloat162float(((__hip_bfloat16*)&bb)[1]));
            float v2 = silu_f(acc[nt][2] + __bfloat162float(((__hip_bfloat16*)&bb)[2]));
            float v3 = silu_f(acc[nt][3] + __bfloat162float(((__hip_bfloat16*)&bb)[3]));
            *reinterpret_cast<bf16x4*>(trbw + nt * 16 + q * 4) = pack4(v0, v1, v2, v3);
        }
        __builtin_amdgcn_wave_barrier();  // order LDS write->read (per-wave buffer)

        // layer-1 B-frags (h1 matrix [h][b]): lane needs h1[k=kh*32+q*8+j][b=lr]
        // = trb[lr][kh*32+q*8 ..+8) -> contiguous ds_read_b128
        bf16x8 hb0 = *reinterpret_cast<const bf16x8*>(trbw + q * 8);
        bf16x8 hb1 = *reinterpret_cast<const bf16x8*>(trbw + 32 + q * 8);
        __builtin_amdgcn_wave_barrier();

        // ---- layer 1: D1[32g x 16b] = W1_t * h1, 2 M-tiles x 2 K-halves ----
        f32x4 accB[2] = {{0,0,0,0},{0,0,0,0}};
#pragma unroll
        for (int mt = 0; mt < 2; ++mt) {
            bf16x8 aw0 = *reinterpret_cast<const bf16x8*>(w1t + mt * 16 * 72 + rowoff);
            accB[mt] = __builtin_amdgcn_mfma_f32_16x16x32_bf16(aw0, hb0, accB[mt], 0, 0, 0);
            bf16x8 aw1 = *reinterpret_cast<const bf16x8*>(w1t + mt * 16 * 72 + rowoff + 32);
            accB[mt] = __builtin_amdgcn_mfma_f32_16x16x32_bf16(aw1, hb1, accB[mt], 0, 0, 0);
        }
        // ---- layer 2: lane accumulates w2[g]*silu(.) over its 8 g values ----
#pragma unroll
        for (int mt = 0; mt < 2; ++mt) {
            bf16x4 bb = *reinterpret_cast<const bf16x4*>(&b1s[t][mt * 16 + q * 4]);
            bf16x4 ww = *reinterpret_cast<const bf16x4*>(&w2s[t][mt * 16 + q * 4]);
#pragma unroll
            for (int r = 0; r < 4; ++r) {
                float v = silu_f(accB[mt][r] + __bfloat162float(((__hip_bfloat16*)&bb)[r]));
                esum += v * __bfloat162float(((__hip_bfloat16*)&ww)[r]);
            }
        }
        bsum += (t == 0) ? b2r0 : (t == 1) ? b2r1 : (t == 2) ? b2r2 : b2r3;
    }

    // reduce esum over the 4 quads holding the same b (lane bits 4-5)
    esum += __shfl_xor(esum, 16);
    esum += __shfl_xor(esum, 32);

    __syncthreads();   // all waves done with w0s; reuse its space as red[16]
    float* red = reinterpret_cast<float*>(&w0s[0][0][0]);
    if (tid < BT) red[tid] = 0.0f;
    __syncthreads();
    if (q == 0) atomicAdd(&red[lr], esum + bsum);
    __syncthreads();
    if (tid < BT) atomicAdd(&out[b0i + tid], red[tid]);
}

extern "C" void kernel_launch(void* const* d_in, const int* in_sizes, int n_in,
                              void* d_out, int out_size, void* d_ws, size_t ws_size,
                              hipStream_t stream) {
    const float* x  = (const float*)d_in[0];
    const int*   an = (const int*)d_in[1];
    const float* w0 = (const float*)d_in[2];
    const float* b0 = (const float*)d_in[3];
    const float* w1 = (const float*)d_in[4];
    const float* b1 = (const float*)d_in[5];
    const float* w2 = (const float*)d_in[6];
    const float* b2 = (const float*)d_in[7];
    float* out = (float*)d_out;

    hipMemsetAsync(out, 0, B_ * sizeof(float), stream);  // out accumulated via atomics
    dim3 grid(N_ / NCHUNK, B_ / BT);                     // (16, 32) = 512 blocks
    bpnn_kernel<<<grid, 256, 0, stream>>>(x, an, w0, b0, w1, b1, w2, b2, out);
}

// Round 3
// 382.852 us; speedup vs baseline: 1.0403x; 1.0331x over previous
//
#include <hip/hip_runtime.h>
#include <hip/hip_bf16.h>

// BPNN: B=512, N=2048, F=64, T=4, H1=64, H2=32.
// out[b] = sum_n MLP_{t[n]}(x[b,n,:]), MLP = silu(W0 x+b0) -> silu(W1 h+b1) -> w2.h+b2
//
// R3: type-sorted waves. Block = 128 n x 16 b. Prologue sorts the 128 atom
// indices by type (LDS counting sort); wave w processes exactly the atoms of
// type w, so its weight A-fragments are loop-invariant and live in VGPRs
// (loaded once per block from global; weights are 96 KB total -> L2-hot).
// No weight LDS at all -> LDS ~9.4 KB -> occupancy VGPR-bound (~145 regs,
// 3 waves/SIMD = 12 waves/CU), enough in-flight x bytes to saturate HBM.
// MFMA orientation: D = W * x^T (A-frag == B-frag lane mapping, verified R2).

#define B_ 512
#define N_ 2048
#define F_ 64
#define T_ 4
#define H1_ 64
#define H2_ 32

#define BT 16          // b-tile (MFMA N dim)
#define WAVES 4
#define NCHUNK 128     // n per block

typedef __attribute__((ext_vector_type(8))) short bf16x8;
typedef __attribute__((ext_vector_type(4))) short bf16x4;
typedef __attribute__((ext_vector_type(4))) float f32x4;

__device__ inline float silu_f(float v) {
    return v * __builtin_amdgcn_rcpf(1.0f + __expf(-v));
}

__device__ inline bf16x8 pack8(float4 a, float4 b) {
    union { __hip_bfloat162 h[4]; bf16x8 v; } u;
    u.h[0] = __float22bfloat162_rn({a.x, a.y});
    u.h[1] = __float22bfloat162_rn({a.z, a.w});
    u.h[2] = __float22bfloat162_rn({b.x, b.y});
    u.h[3] = __float22bfloat162_rn({b.z, b.w});
    return u.v;
}

__device__ inline bf16x4 pack4(float a, float b, float c, float d) {
    union { __hip_bfloat162 h[2]; bf16x4 v; } u;
    u.h[0] = __float22bfloat162_rn({a, b});
    u.h[1] = __float22bfloat162_rn({c, d});
    return u.v;
}

__device__ inline float bf_at(bf16x4 v, int r) {
    union { bf16x4 v; __hip_bfloat16 h[4]; } u; u.v = v;
    return __bfloat162float(u.h[r]);
}

__global__ __launch_bounds__(256, 3) void bpnn_kernel(
    const float* __restrict__ x, const int* __restrict__ an,
    const float* __restrict__ w0, const float* __restrict__ b0,
    const float* __restrict__ w1, const float* __restrict__ b1,
    const float* __restrict__ w2, const float* __restrict__ b2,
    float* __restrict__ out)
{
    __shared__ __align__(16) __hip_bfloat16 trb[WAVES][BT][68]; // 8704 B transpose buf [b][h]
    __shared__ int sidx[NCHUNK];     // type-sorted n-local indices
    __shared__ int cnt[T_], offs[T_], pos[T_];
    __shared__ float red[BT];

    const int tid  = threadIdx.x;
    const int wave = tid >> 6;
    const int lane = tid & 63;
    const int lr   = lane & 15;      // b-col (B,C) / row (A)
    const int q    = lane >> 4;      // quad
    const int b0i  = blockIdx.y * BT;
    const int n0   = blockIdx.x * NCHUNK;
    const int t    = wave;           // this wave's atom type

    // ---- weight fragments for type t: global -> VGPR, once per block ----
    // A-frag lane mapping (m = lane&15, k = quad*8+j): contiguous 8 floats.
    const float* w0t = w0 + t * (H1_ * F_);
    const float* w1t = w1 + t * (H2_ * H1_);
    bf16x8 aw0[4][2], aw1[2][2];
#pragma unroll
    for (int nt = 0; nt < 4; ++nt)
#pragma unroll
        for (int kh = 0; kh < 2; ++kh) {
            const float4* p = reinterpret_cast<const float4*>(
                w0t + (nt * 16 + lr) * F_ + kh * 32 + q * 8);
            aw0[nt][kh] = pack8(p[0], p[1]);
        }
#pragma unroll
    for (int mt = 0; mt < 2; ++mt)
#pragma unroll
        for (int kh = 0; kh < 2; ++kh) {
            const float4* p = reinterpret_cast<const float4*>(
                w1t + (mt * 16 + lr) * H1_ + kh * 32 + q * 8);
            aw1[mt][kh] = pack8(p[0], p[1]);
        }
    bf16x4 b0f[4], b1f[2], w2f[2];
#pragma unroll
    for (int nt = 0; nt < 4; ++nt) {
        float4 v = *reinterpret_cast<const float4*>(b0 + t * H1_ + nt * 16 + q * 4);
        b0f[nt] = pack4(v.x, v.y, v.z, v.w);
    }
#pragma unroll
    for (int mt = 0; mt < 2; ++mt) {
        float4 v = *reinterpret_cast<const float4*>(b1 + t * H2_ + mt * 16 + q * 4);
        b1f[mt] = pack4(v.x, v.y, v.z, v.w);
        float4 u = *reinterpret_cast<const float4*>(w2 + t * H2_ + mt * 16 + q * 4);
        w2f[mt] = pack4(u.x, u.y, u.z, u.w);
    }
    const float b2t = b2[t];

    // ---- counting sort of the block's atoms by type ----
    if (tid < T_)  cnt[tid] = 0;
    if (tid < BT)  red[tid] = 0.0f;
    __syncthreads();
    int myt = 0;
    if (tid < NCHUNK) { myt = an[n0 + tid]; atomicAdd(&cnt[myt], 1); }
    __syncthreads();
    if (tid == 0) {
        int o = 0;
        for (int k = 0; k < T_; ++k) { offs[k] = o; pos[k] = o; o += cnt[k]; }
    }
    __syncthreads();
    if (tid < NCHUNK) { int p = atomicAdd(&pos[myt], 1); sidx[p] = tid; }
    __syncthreads();

    const int beg = offs[t];
    const int num = __builtin_amdgcn_readfirstlane(cnt[t]);

    const float* xb_ = x + (size_t)(b0i + lr) * (N_ * F_) + (size_t)n0 * F_ + q * 8;
    __hip_bfloat16* trbw = &trb[wave][lr][0];

    float esum = 0.f;   // partial energy for b = b0i+lr (this lane's quad k-slice)

    if (num > 0) {
        // prefetch iter 0 (raw floats stay in regs; pack at consume time)
        int nl = sidx[beg];
        const float4* p0 = reinterpret_cast<const float4*>(xb_ + nl * F_);
        float4 pa = p0[0], pb = p0[1], pc = p0[8], pd = p0[9];

        for (int it = 0; it < num; ++it) {
            // consume current, then immediately issue next iteration's loads
            bf16x8 xf0 = pack8(pa, pb);
            bf16x8 xf1 = pack8(pc, pd);
            {
                int ii = (it + 1 < num) ? (it + 1) : it;
                int nn = sidx[beg + ii];
                const float4* pn = reinterpret_cast<const float4*>(xb_ + nn * F_);
                pa = pn[0]; pb = pn[1]; pc = pn[8]; pd = pn[9];
            }

            // ---- layer 0: D0[64h x 16b] = W0_t * x^T ----
            f32x4 acc[4] = {{0,0,0,0},{0,0,0,0},{0,0,0,0},{0,0,0,0}};
#pragma unroll
            for (int nt = 0; nt < 4; ++nt) {
                acc[nt] = __builtin_amdgcn_mfma_f32_16x16x32_bf16(aw0[nt][0], xf0, acc[nt], 0, 0, 0);
                acc[nt] = __builtin_amdgcn_mfma_f32_16x16x32_bf16(aw0[nt][1], xf1, acc[nt], 0, 0, 0);
            }
            // bias + silu; C-layout lane holds h = nt*16 + q*4 + r, b = lr
#pragma unroll
            for (int nt = 0; nt < 4; ++nt) {
                float v0 = silu_f(acc[nt][0] + bf_at(b0f[nt], 0));
                float v1 = silu_f(acc[nt][1] + bf_at(b0f[nt], 1));
                float v2 = silu_f(acc[nt][2] + bf_at(b0f[nt], 2));
                float v3 = silu_f(acc[nt][3] + bf_at(b0f[nt], 3));
                *reinterpret_cast<bf16x4*>(trbw + nt * 16 + q * 4) = pack4(v0, v1, v2, v3);
            }
            __builtin_amdgcn_wave_barrier();  // order LDS write->read (per-wave buffer)

            bf16x8 hb0 = *reinterpret_cast<const bf16x8*>(trbw + q * 8);
            bf16x8 hb1 = *reinterpret_cast<const bf16x8*>(trbw + 32 + q * 8);
            __builtin_amdgcn_wave_barrier();

            // ---- layer 1: D1[32g x 16b] = W1_t * h1 ----
            f32x4 accB[2] = {{0,0,0,0},{0,0,0,0}};
#pragma unroll
            for (int mt = 0; mt < 2; ++mt) {
                accB[mt] = __builtin_amdgcn_mfma_f32_16x16x32_bf16(aw1[mt][0], hb0, accB[mt], 0, 0, 0);
                accB[mt] = __builtin_amdgcn_mfma_f32_16x16x32_bf16(aw1[mt][1], hb1, accB[mt], 0, 0, 0);
            }
            // ---- layer 2: lane accumulates w2[g]*silu(.) over its 8 g ----
#pragma unroll
            for (int mt = 0; mt < 2; ++mt) {
#pragma unroll
                for (int r = 0; r < 4; ++r) {
                    float v = silu_f(accB[mt][r] + bf_at(b1f[mt], r));
                    esum += v * bf_at(w2f[mt], r);
                }
            }
        }
    }

    // reduce esum over the 4 quads holding the same b (lane bits 4-5)
    esum += __shfl_xor(esum, 16);
    esum += __shfl_xor(esum, 32);
    if (q == 0) atomicAdd(&red[lr], esum + (float)num * b2t);
    __syncthreads();
    if (tid < BT) atomicAdd(&out[b0i + tid], red[tid]);
}

extern "C" void kernel_launch(void* const* d_in, const int* in_sizes, int n_in,
                              void* d_out, int out_size, void* d_ws, size_t ws_size,
                              hipStream_t stream) {
    const float* x  = (const float*)d_in[0];
    const int*   an = (const int*)d_in[1];
    const float* w0 = (const float*)d_in[2];
    const float* b0 = (const float*)d_in[3];
    const float* w1 = (const float*)d_in[4];
    const float* b1 = (const float*)d_in[5];
    const float* w2 = (const float*)d_in[6];
    const float* b2 = (const float*)d_in[7];
    float* out = (float*)d_out;

    hipMemsetAsync(out, 0, B_ * sizeof(float), stream);  // out accumulated via atomics
    dim3 grid(N_ / NCHUNK, B_ / BT);                     // (16, 32) = 512 blocks
    bpnn_kernel<<<grid, 256, 0, stream>>>(x, an, w0, b0, w1, b1, w2, b2, out);
}